// Round 8
// baseline (163.960 us; speedup 1.0000x reference)
//
#include <hip/hip_runtime.h>

// h: (2,1,1,16,16) fp32 | gi: (2,M,16) | gj: (2,M,16) | theta: (2,M) | out: (2,16,16)
//
// History: clean designs all plateau 51-57us / ~4.2 B/cyc/CU delivered:
// R7 LDS DEPTH=3 51 | R8 16w/CU 56.6 | R9 grid-strided front 53.8 |
// R12 VGPR single-buffer 51.5 (VGPR=52) | R14 stream-per-wave copy-shaped
// bursts 53.2. R10/R11 spilled (keep live set < 128: backend spills to meet
// its occupancy target rather than dropping occupancy).
// DECISIVE R14 observation: steady-state replays with hbm_bytes ~1MB (input
// 100% L3-resident) run at the SAME 53-55us as 67MB-fetch runs => the cap is
// NOT DRAM-side. It is the CU->L2/L3 request path: per-CU outstanding-line
// budget x on-die latency ~= 4.2 B/cyc/CU, independent of hit location,
// wave count, pipeline depth, and address pattern.
// R15 (this): last HIP-visible lever on that axis — cache-policy bits.
// All traffic is read-once (zero L1 reuse); default loads still allocate in
// L1 and occupy the default tracking path. __builtin_nontemporal_load sets
// nt (streaming, no L1 allocation; different L2/L3 allocation policy).
// Exact R12 structure, loads/store converted to nontemporal. One variable.
// Pre-commitment: if null (>=50us), eight independent families converge at
// one ceiling => declare ROOFLINE next round.

constexpr int MDIM    = 524288;
constexpr int THREADS = 256;
constexpr int BLOCKS  = 1024;             // 4 blocks/CU at <=128 VGPR
constexpr int M_PER_B = MDIM / BLOCKS;    // 512
constexpr int M_PER_W = M_PER_B / 4;      // 128 m per wave
constexpr int CHUNK   = 16;               // m per chunk
constexpr int NCH     = M_PER_W / CHUNK;  // 8 chunks per wave
static_assert(NCH * BLOCKS * 4 * CHUNK == MDIM, "exact tiling");

typedef float f32x2 __attribute__((ext_vector_type(2)));
typedef float f32x4 __attribute__((ext_vector_type(4)));

// Non-temporal 16B load: emits global_load_dwordx4 with nt (no L1 alloc).
__device__ __forceinline__ f32x4 ldnt4(const float* p) {
    return __builtin_nontemporal_load((const f32x4*)p);
}

template <bool USE_ATOMIC>
__device__ __forceinline__ void theta_body(
    const float* __restrict__ gi, const float* __restrict__ gj,
    const float* __restrict__ theta, float* __restrict__ dst)
{
    const int t    = threadIdx.x;
    const int wave = t >> 6;
    const int lane = t & 63;
    const int slot = (lane >> 4) & 3;            // lane bits 4,5: m sub-group
    const int tile = lane & 15;
    const int i0   = (tile >> 2) << 2;
    const int j0   = (tile & 3) << 2;
    const size_t m0 = (size_t)(blockIdx.x * 4 + wave) * M_PER_W;

    // Per-lane stream pointers with the lane's row/col offset folded in.
    const float* e_p  = gi + (m0 + (size_t)slot * 4) * 16 + i0;
    const float* f_p  = e_p + (size_t)MDIM * 16;
    const float* a_p  = gj + (m0 + (size_t)slot * 4) * 16 + j0;
    const float* b_p  = a_p + (size_t)MDIM * 16;
    const float* t0_p = theta + m0 + (size_t)slot * 4;
    const float* t1_p = t0_p + MDIM;

    f32x2 are[4][2], aim[4][2];
#pragma unroll
    for (int i = 0; i < 4; ++i)
#pragma unroll
        for (int jp = 0; jp < 2; ++jp) { are[i][jp] = {0.f, 0.f}; aim[i][jp] = {0.f, 0.f}; }

    for (int c = 0; c < NCH; ++c) {
        // ---- 18 x 16B non-temporal loads (single buffer, short-lived) ----
        f32x4 e4[4], f4[4], a4[4], b4[4];
#pragma unroll
        for (int k = 0; k < 4; ++k) {
            e4[k] = ldnt4(e_p + k * 16);
            f4[k] = ldnt4(f_p + k * 16);
            a4[k] = ldnt4(a_p + k * 16);
            b4[k] = ldnt4(b_p + k * 16);
        }
        const f32x4 t0v = ldnt4(t0_p);
        const f32x4 t1v = ldnt4(t1_p);
        e_p += CHUNK * 16; f_p += CHUNK * 16;
        a_p += CHUNK * 16; b_p += CHUNK * 16;
        t0_p += CHUNK;     t1_p += CHUNK;

        // ---- compute ----
        const float tc[4] = {t0v.x, t0v.y, t0v.z, t0v.w};
        const float ts[4] = {t1v.x, t1v.y, t1v.z, t1v.w};
#pragma unroll
        for (int k = 0; k < 4; ++k) {
            const float cv = __cosf(tc[k]);
            const float sv = __sinf(ts[k]);
            const f32x2 cc = {cv, cv}, ss = {sv, sv};
            const f32x2 a01 = {a4[k].x, a4[k].y}, a23 = {a4[k].z, a4[k].w};
            const f32x2 b01 = {b4[k].x, b4[k].y}, b23 = {b4[k].z, b4[k].w};
            f32x2 ure[2], uim[2];
            ure[0] = __builtin_elementwise_fma(-b01, ss, a01 * cc);  // a*c - b*s
            ure[1] = __builtin_elementwise_fma(-b23, ss, a23 * cc);
            uim[0] = __builtin_elementwise_fma( b01, cc, a01 * ss);  // a*s + b*c
            uim[1] = __builtin_elementwise_fma( b23, cc, a23 * ss);
            const float ev[4] = {e4[k].x, e4[k].y, e4[k].z, e4[k].w};
            const float fv[4] = {f4[k].x, f4[k].y, f4[k].z, f4[k].w};
#pragma unroll
            for (int i = 0; i < 4; ++i) {
                const f32x2 ee = {ev[i], ev[i]};
                const f32x2 ff = {fv[i], fv[i]};
#pragma unroll
                for (int jp = 0; jp < 2; ++jp) {
                    are[i][jp] = __builtin_elementwise_fma( ee, ure[jp], are[i][jp]);
                    are[i][jp] = __builtin_elementwise_fma(-ff, uim[jp], are[i][jp]);
                    aim[i][jp] = __builtin_elementwise_fma( ee, uim[jp], aim[i][jp]);
                    aim[i][jp] = __builtin_elementwise_fma( ff, ure[jp], aim[i][jp]);
                }
            }
        }
    }

    // Unpack packed accumulators: j = jp*2 + half.
    float sre[4][4], sim[4][4];
#pragma unroll
    for (int i = 0; i < 4; ++i)
#pragma unroll
        for (int jp = 0; jp < 2; ++jp) {
            sre[i][jp * 2]     = are[i][jp].x;  sre[i][jp * 2 + 1] = are[i][jp].y;
            sim[i][jp * 2]     = aim[i][jp].x;  sim[i][jp * 2 + 1] = aim[i][jp].y;
        }

    // Fold the 4 m-slots (lane bits 4,5).
#pragma unroll
    for (int i = 0; i < 4; ++i)
#pragma unroll
        for (int j = 0; j < 4; ++j) {
            sre[i][j] += __shfl_xor(sre[i][j], 16);
            sre[i][j] += __shfl_xor(sre[i][j], 32);
            sim[i][j] += __shfl_xor(sim[i][j], 16);
            sim[i][j] += __shfl_xor(sim[i][j], 32);
        }

    // Fold the 4 waves via LDS (reduction only; 8448 B).
    __shared__ float red[4][16][33];
    if (lane < 16) {
#pragma unroll
        for (int i = 0; i < 4; ++i)
#pragma unroll
            for (int j = 0; j < 4; ++j) {
                red[wave][lane][i * 4 + j]      = sre[i][j];
                red[wave][lane][16 + i * 4 + j] = sim[i][j];
            }
    }
    __syncthreads();

#pragma unroll
    for (int k = 0; k < 2; ++k) {
        const int idx = t * 2 + k;
        const int tl  = idx >> 5;
        const int v   = idx & 31;
        const float sum = red[0][tl][v] + red[1][tl][v] + red[2][tl][v] + red[3][tl][v];
        const int ii  = ((tl >> 2) << 2) + ((v & 15) >> 2);
        const int jj  = ((tl & 3) << 2) + (v & 3);
        const int off = ((v & 16) ? 256 : 0) + ii * 16 + jj;
        if (USE_ATOMIC) atomicAdd(dst + off, sum);
        else            __builtin_nontemporal_store(sum, dst + blockIdx.x * 512 + off);
    }
}

__global__ __launch_bounds__(THREADS) void theta_main_ws(
    const float* __restrict__ gi, const float* __restrict__ gj,
    const float* __restrict__ theta, float* __restrict__ partial)
{
    theta_body<false>(gi, gj, theta, partial);
}

__global__ __launch_bounds__(THREADS) void theta_main_atomic(
    const float* __restrict__ gi, const float* __restrict__ gj,
    const float* __restrict__ theta, float* __restrict__ out)
{
    theta_body<true>(gi, gj, theta, out);
}

// Stage 2: one wave per output element; fold BLOCKS partials + h bias.
__global__ __launch_bounds__(256) void theta_reduce(
    const float* __restrict__ h, const float* __restrict__ partial,
    float* __restrict__ out)
{
    const int w    = (blockIdx.x * 256 + threadIdx.x) >> 6;  // output index 0..511
    const int lane = threadIdx.x & 63;
    float s = 0.f;
#pragma unroll 4
    for (int j = 0; j < BLOCKS / 64; ++j)
        s += partial[(size_t)(j * 64 + lane) * 512 + w];
#pragma unroll
    for (int d = 1; d < 64; d <<= 1) s += __shfl_xor(s, d);
    if (lane == 0) out[w] = h[w] + s;
}

__global__ void theta_init(const float* __restrict__ h, float* __restrict__ out) {
    int k = blockIdx.x * blockDim.x + threadIdx.x;
    if (k < 512) out[k] = h[k];
}

extern "C" void kernel_launch(void* const* d_in, const int* in_sizes, int n_in,
                              void* d_out, int out_size, void* d_ws, size_t ws_size,
                              hipStream_t stream) {
    const float* h     = (const float*)d_in[0];
    const float* gi    = (const float*)d_in[1];
    const float* gj    = (const float*)d_in[2];
    const float* theta = (const float*)d_in[3];
    float* out = (float*)d_out;

    const size_t need = (size_t)BLOCKS * 512 * sizeof(float);  // 2 MB of partials
    if (ws_size >= need) {
        float* partial = (float*)d_ws;
        theta_main_ws<<<BLOCKS, THREADS, 0, stream>>>(gi, gj, theta, partial);
        theta_reduce<<<128, 256, 0, stream>>>(h, partial, out);
    } else {
        theta_init<<<2, 256, 0, stream>>>(h, out);
        theta_main_atomic<<<BLOCKS, THREADS, 0, stream>>>(gi, gj, theta, out);
    }
}